// Round 1
// baseline (218.987 us; speedup 1.0000x reference)
//
#include <hip/hip_runtime.h>

#define LRELU_ALPHA 0.3f
#define BN_EPS 1e-3f

using u16 = unsigned short;
using u32 = unsigned int;

typedef __attribute__((ext_vector_type(8))) short bf16x8;
typedef __attribute__((ext_vector_type(4))) float f32x4;

struct alignas(8) U16x4 { u16 x, y, z, w; };

__device__ __forceinline__ u16 f2bf(float f) {
  union { float f; u32 u; } v; v.f = f;
  u32 b = v.u;
  b += 0x7FFFu + ((b >> 16) & 1u);   // round-to-nearest-even
  return (u16)(b >> 16);
}
__device__ __forceinline__ float bf2f(u16 h) {
  union { u32 u; float f; } v; v.u = ((u32)h) << 16;
  return v.f;
}

typedef const __attribute__((address_space(1))) void* gas_ptr;
typedef __attribute__((address_space(3))) void* las_ptr;

__device__ __forceinline__ void gload16(const void* g, void* l) {
  __builtin_amdgcn_global_load_lds((gas_ptr)g, (las_ptr)l, 16, 0, 0);
}

// ---------------------------------------------------------------------------
// Shared GEMM core: C(128x128) = A(128xK) * B^T(128xK)^T, bf16 in, fp32 acc.
// A: tile base, row stride K elems (contiguous k).
// B: tile base of B^T, row stride K elems (rows = output cols, contiguous k).
// 256 threads = 4 waves in 2x2 arrangement, each wave owns 64x64 (4x4 frags).
// 2-phase double-buffered global_load_lds staging (T3 minimum recipe).
// ---------------------------------------------------------------------------
template <int K>
__device__ __forceinline__ void gemm_core(const u16* __restrict__ A,
                                          const u16* __restrict__ B,
                                          u16* lds,            // 32768 u16 (64 KiB)
                                          f32x4 (&acc)[4][4]) {
  const int t    = threadIdx.x;
  const int lane = t & 63;
  const int wid  = t >> 6;
  const int wm   = (wid >> 1) * 64;
  const int wn   = (wid & 1) * 64;
  const int lrow = lane & 15;
  const int lk   = (lane >> 4) * 8;

  // staging decomposition: per call, thread t moves 16B; flat elem off = cc*2048 + t*8
  const int r0 = t >> 3;          // row within 32-row chunk
  const int ce = (t & 7) * 8;     // col elems within row
  const int lo = (t >> 6) * 512;  // wave-uniform LDS elem offset

  auto stage = [&](int buf, int kt) {
    u16* ldsA = lds + buf * 16384;
    u16* ldsB = ldsA + 8192;
    const u16* gA = A + kt * 64;
    const u16* gB = B + kt * 64;
#pragma unroll
    for (int cc = 0; cc < 4; ++cc) {
      gload16(gA + (size_t)(cc * 32 + r0) * K + ce, ldsA + cc * 2048 + lo);
      gload16(gB + (size_t)(cc * 32 + r0) * K + ce, ldsB + cc * 2048 + lo);
    }
  };

  auto compute = [&](int buf) {
    const u16* As = lds + buf * 16384;
    const u16* Bs = As + 8192;
#pragma unroll
    for (int kk = 0; kk < 2; ++kk) {
      bf16x8 a[4], b[4];
#pragma unroll
      for (int i = 0; i < 4; ++i)
        a[i] = *(const bf16x8*)(As + (wm + i * 16 + lrow) * 64 + kk * 32 + lk);
#pragma unroll
      for (int i = 0; i < 4; ++i)
        b[i] = *(const bf16x8*)(Bs + (wn + i * 16 + lrow) * 64 + kk * 32 + lk);
#pragma unroll
      for (int i = 0; i < 4; ++i)
#pragma unroll
        for (int j = 0; j < 4; ++j)
          acc[i][j] = __builtin_amdgcn_mfma_f32_16x16x32_bf16(a[i], b[j], acc[i][j], 0, 0, 0);
    }
  };

  const int KT = K / 64;
  stage(0, 0);
  asm volatile("s_waitcnt vmcnt(0)" ::: "memory");
  __syncthreads();
  int cur = 0;
#pragma unroll 1
  for (int kt = 0; kt < KT - 1; ++kt) {
    stage(cur ^ 1, kt + 1);       // prefetch next tile into other buffer
    compute(cur);                 // MFMA on current
    asm volatile("s_waitcnt vmcnt(0)" ::: "memory");
    __syncthreads();
    cur ^= 1;
  }
  compute(cur);
}

#define ACC_INIT()                                  \
  f32x4 acc[4][4];                                  \
  _Pragma("unroll") for (int i_ = 0; i_ < 4; ++i_)  \
  _Pragma("unroll") for (int j_ = 0; j_ < 4; ++j_)  \
      acc[i_][j_] = {0.f, 0.f, 0.f, 0.f};

// ---------------------------------------------------------------------------
// prep kernels
// ---------------------------------------------------------------------------
__global__ void k_prep_bn(const float* __restrict__ g1, const float* __restrict__ be1,
                          const float* __restrict__ m1, const float* __restrict__ v1,
                          const float* __restrict__ g2, const float* __restrict__ be2,
                          const float* __restrict__ m2, const float* __restrict__ v2,
                          float* __restrict__ s1, float* __restrict__ t1,
                          float* __restrict__ s2, float* __restrict__ t2c) {
  int c = threadIdx.x;   // 256
  float a1 = g1[c] * rsqrtf(v1[c] + BN_EPS);
  s1[c] = a1; t1[c] = be1[c] - m1[c] * a1;
  float a2 = g2[c] * rsqrtf(v2[c] + BN_EPS);
  s2[c] = a2; t2c[c] = be2[c] - m2[c] * a2;
}

// wcatT[co][ci] = (co<256 ? w1 : w_skip)[ci][co%256];  w2T[co][ci] = w2[ci][co]
__global__ void k_prep_w(const float* __restrict__ w1, const float* __restrict__ wsk,
                         const float* __restrict__ w2,
                         u16* __restrict__ wcatT, u16* __restrict__ w2T) {
  int i = blockIdx.x * 256 + threadIdx.x;
  if (i < 131072) {
    int co = i >> 8, ci = i & 255;
    const float* w = (co < 256) ? w1 : wsk;
    wcatT[i] = f2bf(w[ci * 256 + (co & 255)]);
  } else if (i < 196608) {
    int k = i - 131072;
    int co = k >> 8, ci = k & 255;
    w2T[k] = f2bf(w2[ci * 256 + co]);
  }
}

// adj -> bf16 ; h = BN1(x) -> bf16
__global__ void k_convert(const float* __restrict__ adj, const float* __restrict__ x,
                          const float* __restrict__ s1, const float* __restrict__ t1,
                          u16* __restrict__ adj_bf, u16* __restrict__ h_bf) {
  const int NA = 4194304;   // adj float4 count (16*1024*1024/4)
  const int NH = 1048576;   // x   float4 count (16*1024*256/4)
  int stride = gridDim.x * blockDim.x;
  for (int idx = blockIdx.x * blockDim.x + threadIdx.x; idx < NA + NH; idx += stride) {
    if (idx < NA) {
      float4 v = ((const float4*)adj)[idx];
      U16x4 o = {f2bf(v.x), f2bf(v.y), f2bf(v.z), f2bf(v.w)};
      ((U16x4*)adj_bf)[idx] = o;
    } else {
      int k = idx - NA;
      float4 v = ((const float4*)x)[k];
      int c = (k << 2) & 255;
      U16x4 o = {f2bf(v.x * s1[c] + t1[c]),     f2bf(v.y * s1[c + 1] + t1[c + 1]),
                 f2bf(v.z * s1[c + 2] + t1[c + 2]), f2bf(v.w * s1[c + 3] + t1[c + 3])};
      ((U16x4*)h_bf)[k] = o;
    }
  }
}

// ---------------------------------------------------------------------------
// GEMM 1: hwT[b][co][n] = sum_c h[(b,n)][c] * wcatT[co][c]     (M=16384,N=512,K=256)
// ---------------------------------------------------------------------------
__global__ __launch_bounds__(256) void k_xw(const u16* __restrict__ h_bf,
                                            const u16* __restrict__ wcatT,
                                            u16* __restrict__ hwT) {
  __shared__ u16 lds[32768];
  ACC_INIT();
  const int mt = blockIdx.x, nt = blockIdx.y;
  gemm_core<256>(h_bf + (size_t)mt * 128 * 256, wcatT + (size_t)nt * 128 * 256, lds, acc);

  const int t = threadIdx.x, lane = t & 63, wid = t >> 6;
  const int rm0 = mt * 128 + (wid >> 1) * 64 + (lane >> 4) * 4;
  const int cn0 = nt * 128 + (wid & 1) * 64 + (lane & 15);
#pragma unroll
  for (int i = 0; i < 4; ++i) {
    int mm = rm0 + i * 16;
    int b = mm >> 10, n0 = mm & 1023;
#pragma unroll
    for (int j = 0; j < 4; ++j) {
      int co = cn0 + j * 16;
      U16x4 p = {f2bf(acc[i][j][0]), f2bf(acc[i][j][1]), f2bf(acc[i][j][2]), f2bf(acc[i][j][3])};
      *(U16x4*)(hwT + (((size_t)(b * 512 + co)) << 10) + n0) = p;   // transposed write
    }
  }
}

// ---------------------------------------------------------------------------
// GEMM 2 (big, conv1+skip fused): Y[b][n][c] = sum_m adj[b][n][m]*hw[b][m][c], c in [0,512)
//   c<256 : u2 = BN2(lrelu(Y+b1))                -> u2 bf16 [b][n][c]
//   c>=256: skip = Y + b_skip  (fp32, straight into d_out)
// ---------------------------------------------------------------------------
__global__ __launch_bounds__(256) void k_big1(const u16* __restrict__ adj_bf,
                                              const u16* __restrict__ hwT,
                                              const float* __restrict__ b1,
                                              const float* __restrict__ bsk,
                                              const float* __restrict__ s2,
                                              const float* __restrict__ t2c,
                                              u16* __restrict__ u2b,
                                              float* __restrict__ outp) {
  __shared__ u16 lds[32768];
  ACC_INIT();
  const int mt = blockIdx.x, nt = blockIdx.y, bz = blockIdx.z;
  gemm_core<1024>(adj_bf + ((size_t)bz << 20) + (size_t)mt * 128 * 1024,
                  hwT    + ((size_t)bz << 19) + (size_t)nt * 128 * 1024, lds, acc);

  const int t = threadIdx.x, lane = t & 63, wid = t >> 6;
  const int rn0 = mt * 128 + (wid >> 1) * 64 + (lane >> 4) * 4;
  const int cn0 = nt * 128 + (wid & 1) * 64 + (lane & 15);
#pragma unroll
  for (int j = 0; j < 4; ++j) {
    int c = cn0 + j * 16;
    if (c < 256) {
      float bias = b1[c], sc = s2[c], tc = t2c[c];
      u16* dst = u2b + ((size_t)bz << 18) + c;
#pragma unroll
      for (int i = 0; i < 4; ++i)
#pragma unroll
        for (int r = 0; r < 4; ++r) {
          int n = rn0 + i * 16 + r;
          float y = acc[i][j][r] + bias;
          float u = (y >= 0.f) ? y : LRELU_ALPHA * y;
          dst[(size_t)n << 8] = f2bf(u * sc + tc);
        }
    } else {
      int cc = c - 256;
      float bias = bsk[cc];
      float* dst = outp + ((size_t)bz << 18) + cc;
#pragma unroll
      for (int i = 0; i < 4; ++i)
#pragma unroll
        for (int r = 0; r < 4; ++r) {
          int n = rn0 + i * 16 + r;
          dst[(size_t)n << 8] = acc[i][j][r] + bias;   // skip path, no activation
        }
    }
  }
}

// ---------------------------------------------------------------------------
// GEMM 3 (small, operand-swapped): t2T[b][co][n] = sum_c w2T[co][c] * u2[b][n][c]
//   (M=256 rows of w2T, cols = n, K=256) -> output directly in B^T layout
// ---------------------------------------------------------------------------
__global__ __launch_bounds__(256) void k_sm2(const u16* __restrict__ w2T,
                                             const u16* __restrict__ u2b,
                                             u16* __restrict__ t2T) {
  __shared__ u16 lds[32768];
  ACC_INIT();
  const int mt = blockIdx.x, nt = blockIdx.y, bz = blockIdx.z;
  gemm_core<256>(w2T + (size_t)mt * 128 * 256,
                 u2b + ((size_t)bz << 18) + (size_t)nt * 128 * 256, lds, acc);

  const int t = threadIdx.x, lane = t & 63, wid = t >> 6;
  const int rc0 = mt * 128 + (wid >> 1) * 64 + (lane >> 4) * 4;  // c_out
  const int nn0 = nt * 128 + (wid & 1) * 64 + (lane & 15);       // n
  u16* base = t2T + ((size_t)bz << 18);
#pragma unroll
  for (int i = 0; i < 4; ++i)
#pragma unroll
    for (int j = 0; j < 4; ++j) {
      int n = nn0 + j * 16;
#pragma unroll
      for (int r = 0; r < 4; ++r) {
        int co = rc0 + i * 16 + r;
        base[((size_t)co << 10) + n] = f2bf(acc[i][j][r]);
      }
    }
}

// ---------------------------------------------------------------------------
// GEMM 4 (big): out[b][n][c] = lrelu( sum_m adj[b][n][m]*t2[b][m][c] + b2[c] ) + skip
// ---------------------------------------------------------------------------
__global__ __launch_bounds__(256) void k_big2(const u16* __restrict__ adj_bf,
                                              const u16* __restrict__ t2T,
                                              const float* __restrict__ b2,
                                              float* __restrict__ outp) {
  __shared__ u16 lds[32768];
  ACC_INIT();
  const int mt = blockIdx.x, nt = blockIdx.y, bz = blockIdx.z;
  gemm_core<1024>(adj_bf + ((size_t)bz << 20) + (size_t)mt * 128 * 1024,
                  t2T    + ((size_t)bz << 18) + (size_t)nt * 128 * 1024, lds, acc);

  const int t = threadIdx.x, lane = t & 63, wid = t >> 6;
  const int rn0 = mt * 128 + (wid >> 1) * 64 + (lane >> 4) * 4;
  const int cn0 = nt * 128 + (wid & 1) * 64 + (lane & 15);
#pragma unroll
  for (int j = 0; j < 4; ++j) {
    int c = cn0 + j * 16;
    float bias = b2[c];
#pragma unroll
    for (int i = 0; i < 4; ++i)
#pragma unroll
      for (int r = 0; r < 4; ++r) {
        int n = rn0 + i * 16 + r;
        size_t off = ((size_t)bz << 18) + ((size_t)n << 8) + c;
        float y = acc[i][j][r] + bias;
        float o = ((y >= 0.f) ? y : LRELU_ALPHA * y) + outp[off];  // + skip (stored by k_big1)
        outp[off] = o;
      }
  }
}

// ---------------------------------------------------------------------------
extern "C" void kernel_launch(void* const* d_in, const int* in_sizes, int n_in,
                              void* d_out, int out_size, void* d_ws, size_t ws_size,
                              hipStream_t stream) {
  const float* x   = (const float*)d_in[0];
  const float* adj = (const float*)d_in[1];
  const float* g1  = (const float*)d_in[2];
  const float* be1 = (const float*)d_in[3];
  const float* mu1 = (const float*)d_in[4];
  const float* v1  = (const float*)d_in[5];
  const float* w1  = (const float*)d_in[6];
  const float* b1  = (const float*)d_in[7];
  const float* g2  = (const float*)d_in[8];
  const float* be2 = (const float*)d_in[9];
  const float* mu2 = (const float*)d_in[10];
  const float* v2  = (const float*)d_in[11];
  const float* w2  = (const float*)d_in[12];
  const float* b2  = (const float*)d_in[13];
  const float* wsk = (const float*)d_in[14];
  const float* bsk = (const float*)d_in[15];
  float* out = (float*)d_out;

  char* ws = (char*)d_ws;
  u16*   adj_bf = (u16*)(ws);                    // 33,554,432 B
  u16*   hwT    = (u16*)(ws + 33554432);         // 16,777,216 B
  u16*   h_bf   = (u16*)(ws + 50331648);         //  8,388,608 B
  u16*   u2b    = (u16*)(ws + 58720256);         //  8,388,608 B
  u16*   t2T    = (u16*)(ws + 67108864);         //  8,388,608 B
  u16*   wcatT  = (u16*)(ws + 75497472);         //    262,144 B
  u16*   w2T    = (u16*)(ws + 75759616);         //    131,072 B
  float* s1     = (float*)(ws + 75890688);
  float* t1     = (float*)(ws + 75891712);
  float* s2     = (float*)(ws + 75892736);
  float* t2c    = (float*)(ws + 75893760);
  if (ws_size < 75894784) return;  // guard: leaves out zeroed -> distinct failure signature

  k_prep_bn<<<1, 256, 0, stream>>>(g1, be1, mu1, v1, g2, be2, mu2, v2, s1, t1, s2, t2c);
  k_prep_w <<<768, 256, 0, stream>>>(w1, wsk, w2, wcatT, w2T);
  k_convert<<<2048, 256, 0, stream>>>(adj, x, s1, t1, adj_bf, h_bf);
  k_xw  <<<dim3(128, 4),    256, 0, stream>>>(h_bf, wcatT, hwT);
  k_big1<<<dim3(8, 4, 16),  256, 0, stream>>>(adj_bf, hwT, b1, bsk, s2, t2c, u2b, out);
  k_sm2 <<<dim3(2, 8, 16),  256, 0, stream>>>(w2T, u2b, t2T);
  k_big2<<<dim3(8, 2, 16),  256, 0, stream>>>(adj_bf, t2T, b2, out);
}

// Round 2
// 216.878 us; speedup vs baseline: 1.0097x; 1.0097x over previous
//
#include <hip/hip_runtime.h>

#define LRELU_ALPHA 0.3f
#define BN_EPS 1e-3f

using u16 = unsigned short;
using u32 = unsigned int;

typedef __attribute__((ext_vector_type(8))) short bf16x8;
typedef __attribute__((ext_vector_type(4))) float f32x4;

struct alignas(8) U16x4 { u16 x, y, z, w; };

__device__ __forceinline__ u16 f2bf(float f) {
  union { float f; u32 u; } v; v.f = f;
  u32 b = v.u;
  b += 0x7FFFu + ((b >> 16) & 1u);   // round-to-nearest-even
  return (u16)(b >> 16);
}
__device__ __forceinline__ float bf2f(u16 h) {
  union { u32 u; float f; } v; v.u = ((u32)h) << 16;
  return v.f;
}

typedef const __attribute__((address_space(1))) void* gas_ptr;
typedef __attribute__((address_space(3))) void* las_ptr;

__device__ __forceinline__ void gload16(const void* g, void* l) {
  __builtin_amdgcn_global_load_lds((gas_ptr)g, (las_ptr)l, 16, 0, 0);
}

// ---------------------------------------------------------------------------
// Shared GEMM core: C(128x128) = A(128xK) * B^T(128xK)^T, bf16 in, fp32 acc.
// 256 threads = 4 waves in 2x2; each wave owns 64x64 (4x4 16x16 frags).
// 2-phase double-buffered global_load_lds staging.
// ---------------------------------------------------------------------------
template <int K>
__device__ __forceinline__ void gemm_core(const u16* __restrict__ A,
                                          const u16* __restrict__ B,
                                          u16* lds,            // 32768 u16 (64 KiB)
                                          f32x4 (&acc)[4][4]) {
  const int t    = threadIdx.x;
  const int lane = t & 63;
  const int wid  = t >> 6;
  const int wm   = (wid >> 1) * 64;
  const int wn   = (wid & 1) * 64;
  const int lrow = lane & 15;
  const int lk   = (lane >> 4) * 8;

  const int r0 = t >> 3;          // row within 32-row chunk
  const int ce = (t & 7) * 8;     // col elems within row
  const int lo = (t >> 6) * 512;  // wave-uniform LDS elem offset

  auto stage = [&](int buf, int kt) {
    u16* ldsA = lds + buf * 16384;
    u16* ldsB = ldsA + 8192;
    const u16* gA = A + kt * 64;
    const u16* gB = B + kt * 64;
#pragma unroll
    for (int cc = 0; cc < 4; ++cc) {
      gload16(gA + (size_t)(cc * 32 + r0) * K + ce, ldsA + cc * 2048 + lo);
      gload16(gB + (size_t)(cc * 32 + r0) * K + ce, ldsB + cc * 2048 + lo);
    }
  };

  auto compute = [&](int buf) {
    const u16* As = lds + buf * 16384;
    const u16* Bs = As + 8192;
#pragma unroll
    for (int kk = 0; kk < 2; ++kk) {
      bf16x8 a[4], b[4];
#pragma unroll
      for (int i = 0; i < 4; ++i)
        a[i] = *(const bf16x8*)(As + (wm + i * 16 + lrow) * 64 + kk * 32 + lk);
#pragma unroll
      for (int i = 0; i < 4; ++i)
        b[i] = *(const bf16x8*)(Bs + (wn + i * 16 + lrow) * 64 + kk * 32 + lk);
#pragma unroll
      for (int i = 0; i < 4; ++i)
#pragma unroll
        for (int j = 0; j < 4; ++j)
          acc[i][j] = __builtin_amdgcn_mfma_f32_16x16x32_bf16(a[i], b[j], acc[i][j], 0, 0, 0);
    }
  };

  const int KT = K / 64;
  stage(0, 0);
  asm volatile("s_waitcnt vmcnt(0)" ::: "memory");
  __syncthreads();
  int cur = 0;
#pragma unroll 1
  for (int kt = 0; kt < KT - 1; ++kt) {
    stage(cur ^ 1, kt + 1);
    compute(cur);
    asm volatile("s_waitcnt vmcnt(0)" ::: "memory");
    __syncthreads();
    cur ^= 1;
  }
  compute(cur);
}

#define ACC_INIT()                                  \
  f32x4 acc[4][4];                                  \
  _Pragma("unroll") for (int i_ = 0; i_ < 4; ++i_)  \
  _Pragma("unroll") for (int j_ = 0; j_ < 4; ++j_)  \
      acc[i_][j_] = {0.f, 0.f, 0.f, 0.f};

#define EPI_COORDS()                                          \
  const int t = threadIdx.x, lane = t & 63, wid = t >> 6;     \
  const int row0 = (wid >> 1) * 64 + (lane >> 4) * 4;         \
  const int col0 = (wid & 1) * 64 + (lane & 15);

// ---------------------------------------------------------------------------
// merged prep: BN fold + weight transpose/pack
// ---------------------------------------------------------------------------
__global__ void k_prep(const float* __restrict__ w1, const float* __restrict__ wsk,
                       const float* __restrict__ w2,
                       const float* __restrict__ g1, const float* __restrict__ be1,
                       const float* __restrict__ m1, const float* __restrict__ v1,
                       const float* __restrict__ g2, const float* __restrict__ be2,
                       const float* __restrict__ m2, const float* __restrict__ v2,
                       u16* __restrict__ wcatT, u16* __restrict__ w2T,
                       float* __restrict__ s1, float* __restrict__ t1,
                       float* __restrict__ s2, float* __restrict__ t2c) {
  if (blockIdx.x == 0) {
    int c = threadIdx.x;
    float a1 = g1[c] * rsqrtf(v1[c] + BN_EPS);
    s1[c] = a1; t1[c] = be1[c] - m1[c] * a1;
    float a2 = g2[c] * rsqrtf(v2[c] + BN_EPS);
    s2[c] = a2; t2c[c] = be2[c] - m2[c] * a2;
  }
  int i = blockIdx.x * 256 + threadIdx.x;
  if (i < 131072) {
    int co = i >> 8, ci = i & 255;
    const float* w = (co < 256) ? w1 : wsk;
    wcatT[i] = f2bf(w[ci * 256 + (co & 255)]);
  } else if (i < 196608) {
    int k = i - 131072;
    int co = k >> 8, ci = k & 255;
    w2T[k] = f2bf(w2[ci * 256 + co]);
  }
}

// adj -> bf16 ; h = BN1(x) -> bf16
__global__ void k_convert(const float* __restrict__ adj, const float* __restrict__ x,
                          const float* __restrict__ s1, const float* __restrict__ t1,
                          u16* __restrict__ adj_bf, u16* __restrict__ h_bf) {
  const int NA = 4194304;   // adj float4 count
  const int NH = 1048576;   // x   float4 count
  int stride = gridDim.x * blockDim.x;
  for (int idx = blockIdx.x * blockDim.x + threadIdx.x; idx < NA + NH; idx += stride) {
    if (idx < NA) {
      float4 v = ((const float4*)adj)[idx];
      U16x4 o = {f2bf(v.x), f2bf(v.y), f2bf(v.z), f2bf(v.w)};
      ((U16x4*)adj_bf)[idx] = o;
    } else {
      int k = idx - NA;
      float4 v = ((const float4*)x)[k];
      int c = (k << 2) & 255;
      U16x4 o = {f2bf(v.x * s1[c] + t1[c]),         f2bf(v.y * s1[c + 1] + t1[c + 1]),
                 f2bf(v.z * s1[c + 2] + t1[c + 2]), f2bf(v.w * s1[c + 3] + t1[c + 3])};
      ((U16x4*)h_bf)[k] = o;
    }
  }
}

// ---------------------------------------------------------------------------
// GEMM 1: hwT[b][co][n] = sum_c h[(b,n)][c] * wcatT[co][c]   (M=16384,N=512,K=256)
// transposed write staged through LDS -> contiguous 16B stores
// ---------------------------------------------------------------------------
__global__ __launch_bounds__(256) void k_xw(const u16* __restrict__ h_bf,
                                            const u16* __restrict__ wcatT,
                                            u16* __restrict__ hwT) {
  __shared__ u16 lds[32768];
  ACC_INIT();
  const int mt = blockIdx.x, nt = blockIdx.y;
  gemm_core<256>(h_bf + (size_t)mt * 128 * 256, wcatT + (size_t)nt * 128 * 256, lds, acc);

  EPI_COORDS();
  __syncthreads();
  u16* tl = lds;                       // [co][m] stride 136
#pragma unroll
  for (int j = 0; j < 4; ++j) {
    int co_l = col0 + j * 16;
#pragma unroll
    for (int i = 0; i < 4; ++i)
#pragma unroll
      for (int r = 0; r < 4; ++r)
        tl[co_l * 136 + row0 + i * 16 + r] = f2bf(acc[i][j][r]);
  }
  __syncthreads();
  const int rw = t >> 4, seg = t & 15;
  const int b = mt >> 3, nb = (mt & 7) * 128;
#pragma unroll
  for (int p = 0; p < 8; ++p) {
    int co_l = p * 16 + rw;
    *(bf16x8*)(hwT + (((size_t)(b * 512 + nt * 128 + co_l)) << 10) + nb + seg * 8) =
        *(const bf16x8*)(tl + co_l * 136 + seg * 8);
  }
}

// ---------------------------------------------------------------------------
// GEMM 2 (big, conv1+skip fused): Y[b][n][c] = sum_m adj[b][n][m]*hw[b][m][c]
//   nt<2  (c<256) : u2   = BN2(lrelu(Y+b1))  -> bf16 [b][n][c]
//   nt>=2 (c>=256): skip = Y + b_skip        -> bf16 [b][n][cc]
// ---------------------------------------------------------------------------
__global__ __launch_bounds__(256) void k_big1(const u16* __restrict__ adj_bf,
                                              const u16* __restrict__ hwT,
                                              const float* __restrict__ b1,
                                              const float* __restrict__ bsk,
                                              const float* __restrict__ s2,
                                              const float* __restrict__ t2c,
                                              u16* __restrict__ u2b,
                                              u16* __restrict__ skipb) {
  __shared__ u16 lds[32768];
  ACC_INIT();
  const int mt = blockIdx.x, nt = blockIdx.y, bz = blockIdx.z;
  gemm_core<1024>(adj_bf + ((size_t)bz << 20) + (size_t)mt * 128 * 1024,
                  hwT    + ((size_t)bz << 19) + (size_t)nt * 128 * 1024, lds, acc);

  EPI_COORDS();
  const bool conv = (nt < 2);          // block-uniform
  const int cb = (nt & 1) * 128;
  __syncthreads();
  u16* tl = lds;                       // [n][c] stride 136
#pragma unroll
  for (int j = 0; j < 4; ++j) {
    int cl = col0 + j * 16;
    int c = cb + cl;
    float bias = conv ? b1[c] : bsk[c];
    float sc = s2[c], tc = t2c[c];
#pragma unroll
    for (int i = 0; i < 4; ++i)
#pragma unroll
      for (int r = 0; r < 4; ++r) {
        float y = acc[i][j][r] + bias;
        float v;
        if (conv) {
          float u = (y >= 0.f) ? y : LRELU_ALPHA * y;
          v = fmaf(u, sc, tc);
        } else {
          v = y;
        }
        tl[(row0 + i * 16 + r) * 136 + cl] = f2bf(v);
      }
  }
  __syncthreads();
  u16* dstbase = (conv ? u2b : skipb) + ((size_t)bz << 18) + cb;
  const int rw = t >> 4, seg = t & 15;
  const int nb = mt * 128;
#pragma unroll
  for (int p = 0; p < 8; ++p) {
    int nl = p * 16 + rw;
    *(bf16x8*)(dstbase + ((size_t)(nb + nl) << 8) + seg * 8) =
        *(const bf16x8*)(tl + nl * 136 + seg * 8);
  }
}

// ---------------------------------------------------------------------------
// GEMM 3 (operand-swapped): t2T[b][co][n] = sum_c w2T[co][c] * u2[b][n][c]
// ---------------------------------------------------------------------------
__global__ __launch_bounds__(256) void k_sm2(const u16* __restrict__ w2T,
                                             const u16* __restrict__ u2b,
                                             u16* __restrict__ t2T) {
  __shared__ u16 lds[32768];
  ACC_INIT();
  const int mt = blockIdx.x, nt = blockIdx.y, bz = blockIdx.z;
  gemm_core<256>(w2T + (size_t)mt * 128 * 256,
                 u2b + ((size_t)bz << 18) + (size_t)nt * 128 * 256, lds, acc);

  EPI_COORDS();
  __syncthreads();
  u16* tl = lds;                       // [co][n] stride 136
#pragma unroll
  for (int j = 0; j < 4; ++j) {
    int nl = col0 + j * 16;
#pragma unroll
    for (int i = 0; i < 4; ++i)
#pragma unroll
      for (int r = 0; r < 4; ++r)
        tl[(row0 + i * 16 + r) * 136 + nl] = f2bf(acc[i][j][r]);
  }
  __syncthreads();
  const int rw = t >> 4, seg = t & 15;
  u16* base = t2T + ((size_t)bz << 18) + nt * 128;
#pragma unroll
  for (int p = 0; p < 8; ++p) {
    int co_l = p * 16 + rw;
    *(bf16x8*)(base + (((size_t)(mt * 128 + co_l)) << 10) + seg * 8) =
        *(const bf16x8*)(tl + co_l * 136 + seg * 8);
  }
}

// ---------------------------------------------------------------------------
// GEMM 4 (big): out = lrelu( adj @ t2 + b2 ) + skip     (fp32 out, coalesced)
// ---------------------------------------------------------------------------
__global__ __launch_bounds__(256) void k_big2(const u16* __restrict__ adj_bf,
                                              const u16* __restrict__ t2T,
                                              const float* __restrict__ b2,
                                              const u16* __restrict__ skipb,
                                              float* __restrict__ outp) {
  __shared__ u16 lds[32768];
  ACC_INIT();
  const int mt = blockIdx.x, nt = blockIdx.y, bz = blockIdx.z;
  gemm_core<1024>(adj_bf + ((size_t)bz << 20) + (size_t)mt * 128 * 1024,
                  t2T    + ((size_t)bz << 18) + (size_t)nt * 128 * 1024, lds, acc);

  EPI_COORDS();
  __syncthreads();
  float* tf = (float*)lds;             // [n][c] stride 128 (64 KiB exactly)
#pragma unroll
  for (int j = 0; j < 4; ++j) {
    int cl = col0 + j * 16;
    float bias = b2[nt * 128 + cl];
#pragma unroll
    for (int i = 0; i < 4; ++i)
#pragma unroll
      for (int r = 0; r < 4; ++r) {
        float y = acc[i][j][r] + bias;
        tf[(row0 + i * 16 + r) * 128 + cl] = (y >= 0.f) ? y : LRELU_ALPHA * y;
      }
  }
  __syncthreads();
  const int rw = t >> 5, seg = t & 31;
  const int cbase = nt * 128;
#pragma unroll
  for (int p = 0; p < 16; ++p) {
    int nl = p * 8 + rw;
    size_t go = ((size_t)bz << 18) + ((size_t)(mt * 128 + nl) << 8) + cbase + seg * 4;
    float4 v = *(const float4*)(tf + nl * 128 + seg * 4);
    U16x4 sk = *(const U16x4*)(skipb + go);
    float4 o = {v.x + bf2f(sk.x), v.y + bf2f(sk.y), v.z + bf2f(sk.z), v.w + bf2f(sk.w)};
    *(float4*)(outp + go) = o;
  }
}

// ---------------------------------------------------------------------------
extern "C" void kernel_launch(void* const* d_in, const int* in_sizes, int n_in,
                              void* d_out, int out_size, void* d_ws, size_t ws_size,
                              hipStream_t stream) {
  const float* x   = (const float*)d_in[0];
  const float* adj = (const float*)d_in[1];
  const float* g1  = (const float*)d_in[2];
  const float* be1 = (const float*)d_in[3];
  const float* mu1 = (const float*)d_in[4];
  const float* v1  = (const float*)d_in[5];
  const float* w1  = (const float*)d_in[6];
  const float* b1  = (const float*)d_in[7];
  const float* g2  = (const float*)d_in[8];
  const float* be2 = (const float*)d_in[9];
  const float* mu2 = (const float*)d_in[10];
  const float* v2  = (const float*)d_in[11];
  const float* w2  = (const float*)d_in[12];
  const float* b2  = (const float*)d_in[13];
  const float* wsk = (const float*)d_in[14];
  const float* bsk = (const float*)d_in[15];
  float* out = (float*)d_out;

  char* ws = (char*)d_ws;
  u16*   adj_bf = (u16*)(ws);                    // 33,554,432 B
  u16*   hwT    = (u16*)(ws + 33554432);         // 16,777,216 B
  u16*   h_bf   = (u16*)(ws + 50331648);         //  8,388,608 B
  u16*   u2b    = (u16*)(ws + 58720256);         //  8,388,608 B
  u16*   t2T    = (u16*)(ws + 67108864);         //  8,388,608 B
  u16*   skipb  = (u16*)(ws + 75497472);         //  8,388,608 B
  u16*   wcatT  = (u16*)(ws + 83886080);         //    262,144 B
  u16*   w2T    = (u16*)(ws + 84148224);         //    131,072 B
  float* s1     = (float*)(ws + 84279296);
  float* t1     = (float*)(ws + 84280320);
  float* s2     = (float*)(ws + 84281344);
  float* t2c    = (float*)(ws + 84282368);
  if (ws_size < 84283392) return;

  k_prep   <<<768, 256, 0, stream>>>(w1, wsk, w2, g1, be1, mu1, v1, g2, be2, mu2, v2,
                                     wcatT, w2T, s1, t1, s2, t2c);
  k_convert<<<2048, 256, 0, stream>>>(adj, x, s1, t1, adj_bf, h_bf);
  k_xw  <<<dim3(128, 4),   256, 0, stream>>>(h_bf, wcatT, hwT);
  k_big1<<<dim3(8, 4, 16), 256, 0, stream>>>(adj_bf, hwT, b1, bsk, s2, t2c, u2b, skipb);
  k_sm2 <<<dim3(2, 8, 16), 256, 0, stream>>>(w2T, u2b, t2T);
  k_big2<<<dim3(8, 2, 16), 256, 0, stream>>>(adj_bf, t2T, b2, skipb, out);
}